// Round 1
// baseline (110.336 us; speedup 1.0000x reference)
//
#include <hip/hip_runtime.h>
#include <math.h>

// RoPE: x (B=16, S=8192, D=128) fp32, interleaved even/odd pairs.
// Reference ignores token_positions; angle = s * theta^(-2i/D), i in [0,64).
// out[2i]   = x[2i]*cos - x[2i+1]*sin
// out[2i+1] = x[2i]*sin + x[2i+1]*cos

constexpr int B_DIM = 16;
constexpr int S_DIM = 8192;
constexpr int D_DIM = 128;

// log2(10000)/64 : inv_freq_i = 2^(-i * LOG2_THETA_OVER_HALFD)
#define LOG2_THETA_OVER_HALFD 0.20762050593046014f

__global__ __launch_bounds__(256) void rope_kernel(const float4* __restrict__ x,
                                                   float4* __restrict__ out) {
    const int g = blockIdx.x * blockDim.x + threadIdx.x;   // float4 index
    const int j = g & 31;            // float4 within row (32 float4 per 128-elem row)
    const int row = g >> 5;          // b*S + s
    const int s = row & (S_DIM - 1); // sequence position

    const float4 v = x[g];

    // two frequency indices for this float4: i0 = 2j, i1 = 2j+1
    const float fi0 = (float)(2 * j);
    const float fi1 = fi0 + 1.0f;
    const float inv0 = exp2f(-fi0 * LOG2_THETA_OVER_HALFD);
    const float inv1 = exp2f(-fi1 * LOG2_THETA_OVER_HALFD);

    const float fs = (float)s;
    float s0, c0, s1, c1;
    __sincosf(fs * inv0, &s0, &c0);
    __sincosf(fs * inv1, &s1, &c1);

    float4 o;
    o.x = v.x * c0 - v.y * s0;
    o.y = v.x * s0 + v.y * c0;
    o.z = v.z * c1 - v.w * s1;
    o.w = v.z * s1 + v.w * c1;
    out[g] = o;
}

extern "C" void kernel_launch(void* const* d_in, const int* in_sizes, int n_in,
                              void* d_out, int out_size, void* d_ws, size_t ws_size,
                              hipStream_t stream) {
    const float4* x = (const float4*)d_in[0];
    float4* out = (float4*)d_out;
    const int total_f4 = B_DIM * S_DIM * (D_DIM / 4);  // 4,194,304
    const int block = 256;
    const int grid = total_f4 / block;                 // 16384
    rope_kernel<<<grid, block, 0, stream>>>(x, out);
}